// Round 10
// baseline (1502.305 us; speedup 1.0000x reference)
//
#include <hip/hip_runtime.h>

#define EPS 1e-9f

constexpr int B_ = 8, N_ = 2048, M_ = 2048;
constexpr int THREADS = 512;                 // 8 waves
constexpr int GROUPS = 4;                    // row-groups per block (wave pairs)
constexpr int RPW = 8;                       // rows per group (R6-proven body)
constexpr int RPB = GROUPS * RPW;            // 32 rows per block
constexpr int BPB = N_ / RPB;                // 64 blocks per batch
constexpr int GRID = B_ * BPB;               // 512 blocks = 2/CU x 8 waves = 16 waves/CU
constexpr int MPT = M_ / THREADS;            // 4 cols per thread (staging)
constexpr int KH  = M_ / 2 / 64;             // 16 k-iters per column-half

__global__ __launch_bounds__(256) void init_kernel(float* rL, float* fb,
                                                   float* ss0, float* out) {
    int i = blockIdx.x * blockDim.x + threadIdx.x;
    if (i < B_ * N_) { rL[i] = 1.f; fb[i] = 0.f; ss0[i] = 0.f; }
    if (i < B_) out[i] = 0.f;
}

// One kernel per annealing step s: [phase2 of s-1] + [phase1 of s].
// k-SPLIT wave pairs: wave = (group, half); each wave runs the R6 RPW=8 pass
// body over its column half (KH=16 iters). Row reductions (accd, rowsum)
// combine across the pair via an 8-float LDS exchange. This doubles waves/CU
// (8 -> 16) while keeping the register-heavy body whose codegen R6 proved out
// (R7-R9 showed small bodies -> 56-64 VGPR -> no load-ahead -> 2x stalls).
__global__ __launch_bounds__(THREADS, 4) void fused_step(
        const float* __restrict__ xyz1, const float* __restrict__ xyz2,
        float* __restrict__ rLb, float* __restrict__ fb,
        const float* __restrict__ rRp,   // rR(s-1) in   (unused if !has_p2)
        float* __restrict__ rRn_g,       // rR(s)  out   (designated block)
        const float* __restrict__ ssp_g, // ss(s-1) in   (unused if !has_p2)
        float* __restrict__ ssc_g,       // ss(s) atomic accumulate (pre-zeroed)
        float* __restrict__ ssz_g,       // ss(s+1) zeroed here for next kernel
        float* __restrict__ out,
        float l2p, float l2c, int has_p2, int has_p1)
{
    __shared__ float4 spg[M_];                  // (x,y,z,g)  32 KB; ssl overlay
    __shared__ float4 spr[M_];                  // (x,y,z,rn) 32 KB
    __shared__ float  exA[GROUPS][2][RPW];      // accd cross-half exchange
    __shared__ float  exB[GROUPS][2][RPW];      // rowsum cross-half exchange
    float* ssl = (float*)spg;

    const int b   = blockIdx.x / BPB;
    const int blk = blockIdx.x % BPB;
    const int n0  = blk * RPB;
    const int tid = threadIdx.x;
    const bool designated = (blk == 0);

    // ---- staging: both per-column factor arrays from (rR, ss) of step s-1 ----
    const float* x2 = xyz2 + (size_t)b * M_ * 3;
    #pragma unroll
    for (int i = 0; i < MPT; ++i) {
        const int m = tid + i * THREADS;
        const float x = x2[3*m], y = x2[3*m+1], z = x2[3*m+2];
        float g = 0.f, rn = 1.f;
        if (has_p2) {
            const float rr = rRp[b * M_ + m];
            const float s  = ssp_g[b * M_ + m];
            const float ratio = fminf(rr / (s + EPS), 1.f);
            g  = rr * ratio;
            rn = fmaxf(rr - s * ratio, 0.f);
        }
        spg[m] = make_float4(x, y, z, g);
        spr[m] = make_float4(x, y, z, rn);
        if (designated) {
            if (has_p1) rRn_g[b * M_ + m] = rn;
            ssz_g[b * M_ + m] = 0.f;
        }
    }
    __syncthreads();

    const int wave = tid >> 6, lane = tid & 63;
    const int grp = wave >> 1, half = wave & 1;
    const int nw = n0 + grp * RPW;
    const int mb = half * (M_ / 2) + lane;      // this wave's column-half base

    float xv[RPW], yv[RPW], zv[RPW];
    #pragma unroll
    for (int r = 0; r < RPW; ++r) {
        const float* q = xyz1 + (size_t)(b * N_ + nw + r) * 3;
        xv[r] = q[0]; yv[r] = q[1]; zv[r] = q[2];
    }

    // ---- phase2-part (level s-1): weights g ----
    float rl_new[RPW];
    if (has_p2) {
        float accd[RPW], accc[RPW];
        #pragma unroll
        for (int r = 0; r < RPW; ++r) { accd[r] = 0.f; accc[r] = 0.f; }
        #pragma unroll
        for (int k = 0; k < KH; ++k) {
            const float4 c = spg[mb + (k << 6)];
            #pragma unroll
            for (int r = 0; r < RPW; ++r) {
                const float dx = xv[r]-c.x, dy = yv[r]-c.y, dz = zv[r]-c.z;
                const float d2 = dx*dx + dy*dy + dz*dz;
                const float e = __builtin_amdgcn_exp2f(l2p * d2) * c.w;
                accd[r] += e;
                accc[r] += e * __builtin_amdgcn_sqrtf(fmaxf(d2, 1e-20f));
            }
        }
        #pragma unroll
        for (int r = 0; r < RPW; ++r) {
            #pragma unroll
            for (int off = 32; off >= 1; off >>= 1)
                accd[r] += __shfl_xor(accd[r], off, 64);
        }
        if (lane == 0) {
            #pragma unroll
            for (int r = 0; r < RPW; ++r) exA[grp][half][r] = accd[r];
        }
        // cost: fold wave-uniform f into lane partials, one butterfly
        float fo[RPW];
        float cl = 0.f;
        #pragma unroll
        for (int r = 0; r < RPW; ++r) {
            fo[r] = fb[b * N_ + nw + r];
            cl = fmaf(fo[r], accc[r], cl);
        }
        #pragma unroll
        for (int off = 32; off >= 1; off >>= 1)
            cl += __shfl_xor(cl, off, 64);
        __syncthreads();   // exA complete (both halves)
        #pragma unroll
        for (int r = 0; r < RPW; ++r) {
            const float ad = exA[grp][0][r] + exA[grp][1][r];
            const float rl = rLb[b * N_ + nw + r];
            rl_new[r] = fmaxf(rl - fo[r] * ad, 0.f);
        }
        if (lane == 0) atomicAdd(&out[b], cl);
    } else {
        #pragma unroll
        for (int r = 0; r < RPW; ++r) rl_new[r] = 1.f;
    }

    // ---- phase1-part (level s): weights rn ----
    if (has_p1) {
        // pass A: rowsums over this wave's half, combine across pair
        float p[RPW];
        #pragma unroll
        for (int r = 0; r < RPW; ++r) p[r] = 0.f;
        #pragma unroll
        for (int k = 0; k < KH; ++k) {
            const float4 c = spr[mb + (k << 6)];
            #pragma unroll
            for (int r = 0; r < RPW; ++r) {
                const float dx = xv[r]-c.x, dy = yv[r]-c.y, dz = zv[r]-c.z;
                const float d2 = dx*dx + dy*dy + dz*dz;
                p[r] += __builtin_amdgcn_exp2f(l2c * d2) * c.w;
            }
        }
        #pragma unroll
        for (int r = 0; r < RPW; ++r) {
            #pragma unroll
            for (int off = 32; off >= 1; off >>= 1)
                p[r] += __shfl_xor(p[r], off, 64);
        }
        if (lane == 0) {
            #pragma unroll
            for (int r = 0; r < RPW; ++r) exB[grp][half][r] = p[r];
        }
        __syncthreads();   // exB complete
        float fn[RPW];
        #pragma unroll
        for (int r = 0; r < RPW; ++r) {
            const float pr = exB[grp][0][r] + exB[grp][1][r];
            fn[r] = rl_new[r] * __builtin_amdgcn_rcpf(pr + EPS);
        }
        if (half == 0 && lane == 0) {
            #pragma unroll
            for (int r = 0; r < RPW; ++r) {
                const int idx = b * N_ + nw + r;
                fb[idx]  = fn[r];
                rLb[idx] = rl_new[r];
            }
        }
        // pass B: recompute e, per-lane column sums over this wave's half
        float ssp[KH];
        #pragma unroll
        for (int k = 0; k < KH; ++k) {
            const float4 c = spr[mb + (k << 6)];
            float s = 0.f;
            #pragma unroll
            for (int r = 0; r < RPW; ++r) {
                const float dx = xv[r]-c.x, dy = yv[r]-c.y, dz = zv[r]-c.z;
                const float d2 = dx*dx + dy*dy + dz*dz;
                s = fmaf(__builtin_amdgcn_exp2f(l2c * d2), fn[r], s);
            }
            ssp[k] = s * c.w;
        }
        // ssl overlays spg: all spg reads ended before the exA/exB barriers
        #pragma unroll
        for (int k = 0; k < KH; ++k)
            ssl[grp * M_ + mb + (k << 6)] = ssp[k];
        __syncthreads();
        #pragma unroll
        for (int i = 0; i < MPT; ++i) {
            const int m = tid + i * THREADS;
            atomicAdd(&ssc_g[b * M_ + m],
                      ssl[m] + ssl[M_ + m] + ssl[2*M_ + m] + ssl[3*M_ + m]);
        }
    }
}

extern "C" void kernel_launch(void* const* d_in, const int* in_sizes, int n_in,
                              void* d_out, int out_size, void* d_ws, size_t ws_size,
                              hipStream_t stream) {
    const float* xyz1 = (const float*)d_in[0];
    const float* xyz2 = (const float*)d_in[1];
    float* out = (float*)d_out;
    float* ws = (float*)d_ws;
    const int SZ = B_ * N_;          // == B_*M_ == 16384
    float* rL  = ws;
    float* fb  = ws + SZ;
    float* rRb[2] = { ws + 2*SZ, ws + 3*SZ };
    float* ssb[3] = { ws + 4*SZ, ws + 5*SZ, ws + 6*SZ };

    init_kernel<<<(SZ + 255) / 256, 256, 0, stream>>>(rL, fb, ssb[0], out);

    constexpr float LOG2E = 1.4426950408889634f;
    static const float levels[10] = {
        -16384.f, -4096.f, -1024.f, -256.f, -64.f,
        -16.f, -4.f, -1.f, -0.25f, 0.f
    };
    // kernel s (s=0..10): phase2 of step s-1 (if s>0) + phase1 of step s (if s<10)
    for (int s = 0; s <= 10; ++s) {
        const int has_p2 = (s > 0);
        const int has_p1 = (s < 10);
        const float l2p = has_p2 ? levels[s-1] * LOG2E : 0.f;
        const float l2c = has_p1 ? levels[s]   * LOG2E : 0.f;
        fused_step<<<GRID, THREADS, 0, stream>>>(
            xyz1, xyz2, rL, fb,
            rRb[(s + 1) & 1],      // rR(s-1)
            rRb[s & 1],            // rR(s) out
            ssb[(s + 2) % 3],      // ss(s-1)
            ssb[s % 3],            // ss(s) accumulate (pre-zeroed)
            ssb[(s + 1) % 3],      // ss(s+1) zeroed for next kernel
            out, l2p, l2c, has_p2, has_p1);
    }
}

// Round 11
// 577.468 us; speedup vs baseline: 2.6015x; 2.6015x over previous
//
#include <hip/hip_runtime.h>

#define EPS 1e-9f

constexpr int B_ = 8, N_ = 2048, M_ = 2048;
constexpr int THREADS = 256;
constexpr int WAVES = 4;
constexpr int RPW = 8;                       // rows per wave (R6-proven body)
constexpr int RPB = WAVES * RPW;             // 32 rows per block
constexpr int BPB = N_ / RPB;                // 64 blocks per batch
constexpr int GRID = B_ * BPB;               // 512
constexpr int MPT = M_ / THREADS;            // 8 cols per thread (staging)

__global__ __launch_bounds__(256) void init_kernel(float* rL, float* fb,
                                                   float* ss0, float* out) {
    int i = blockIdx.x * blockDim.x + threadIdx.x;
    if (i < B_ * N_) { rL[i] = 1.f; fb[i] = 0.f; ss0[i] = 0.f; }
    if (i < B_) out[i] = 0.f;
}

// One kernel per annealing step s: [phase2 of s-1] + [phase1 of s], R6 block
// shape (256 thr, 4 waves, RPW=8 — the only shape this compiler codegens well;
// R7-R10 all regressed on reshapes). New vs R6: phase2 and phase1-passA are
// MERGED into one k-loop. For s=1..8, levels[s-1]==4*levels[s] exactly, so
// exp2(l2p*d2) == exp2(l2c*d2)^4 -> one transcendental + two muls (use_pow
// path). LDS: spg=(x,y,z,g) 32KB (+ssl overlay) and srn (rn) 8KB = 41KB.
// s=0 needs no branch: g=0 staged and fb=0 init make every phase2 term vanish.
__global__ __launch_bounds__(THREADS, 2) void fused_step(
        const float* __restrict__ xyz1, const float* __restrict__ xyz2,
        float* __restrict__ rLb, float* __restrict__ fb,
        const float* __restrict__ rRp,   // rR(s-1) in   (unused if !has_p2)
        float* __restrict__ rRn_g,       // rR(s)  out
        const float* __restrict__ ssp_g, // ss(s-1) in   (unused if !has_p2)
        float* __restrict__ ssc_g,       // ss(s) atomic accumulate (pre-zeroed)
        float* __restrict__ ssz_g,       // ss(s+1) zeroed here for next kernel
        float* __restrict__ out,
        float l2p, float l2c, int use_pow, int has_p2, int has_p1)
{
    __shared__ float4 spg[M_];           // (x,y,z,g) 32 KB; ssl overlay at end
    __shared__ float  srn[M_];           // rn         8 KB
    float* ssl = (float*)spg;

    const int b   = blockIdx.x / BPB;
    const int blk = blockIdx.x % BPB;
    const int n0  = blk * RPB;
    const int tid = threadIdx.x;
    const bool designated = (blk == 0);

    // ---- staging ----
    const float* x2 = xyz2 + (size_t)b * M_ * 3;
    #pragma unroll
    for (int i = 0; i < MPT; ++i) {
        const int m = tid + i * THREADS;
        const float x = x2[3*m], y = x2[3*m+1], z = x2[3*m+2];
        float g = 0.f, rn = 1.f;
        if (has_p2) {
            const float rr = rRp[b * M_ + m];
            const float s  = ssp_g[b * M_ + m];
            const float ratio = fminf(rr / (s + EPS), 1.f);
            g  = rr * ratio;
            rn = fmaxf(rr - s * ratio, 0.f);
        }
        spg[m] = make_float4(x, y, z, g);
        srn[m] = rn;
        if (designated) {
            if (has_p1) rRn_g[b * M_ + m] = rn;
            ssz_g[b * M_ + m] = 0.f;
        }
    }
    __syncthreads();

    const int wave = tid >> 6, lane = tid & 63;
    const int nw = n0 + wave * RPW;

    float xv[RPW], yv[RPW], zv[RPW];
    #pragma unroll
    for (int r = 0; r < RPW; ++r) {
        const float* q = xyz1 + (size_t)(b * N_ + nw + r) * 3;
        xv[r] = q[0]; yv[r] = q[1]; zv[r] = q[2];
    }

    // ---- MERGED k-loop: phase2 accumulators (accd, accc) + phase1 rowsums (p) ----
    float accd[RPW], accc[RPW], p[RPW];
    #pragma unroll
    for (int r = 0; r < RPW; ++r) { accd[r] = 0.f; accc[r] = 0.f; p[r] = 0.f; }

    if (use_pow) {
        #pragma unroll
        for (int k = 0; k < 32; ++k) {
            const int m = lane + (k << 6);
            const float4 c = spg[m];
            const float rn = srn[m];
            #pragma unroll
            for (int r = 0; r < RPW; ++r) {
                const float dx = xv[r]-c.x, dy = yv[r]-c.y, dz = zv[r]-c.z;
                const float d2 = dx*dx + dy*dy + dz*dz;
                const float ec = __builtin_amdgcn_exp2f(l2c * d2);
                const float e2 = ec * ec;
                const float epg = (e2 * e2) * c.w;      // exp2(l2p*d2)*g, l2p=4*l2c
                accd[r] += epg;
                const float sd = __builtin_amdgcn_sqrtf(fmaxf(d2, 1e-20f));
                accc[r] = fmaf(epg, sd, accc[r]);
                p[r] = fmaf(ec, rn, p[r]);
            }
        }
    } else {
        #pragma unroll
        for (int k = 0; k < 32; ++k) {
            const int m = lane + (k << 6);
            const float4 c = spg[m];
            const float rn = srn[m];
            #pragma unroll
            for (int r = 0; r < RPW; ++r) {
                const float dx = xv[r]-c.x, dy = yv[r]-c.y, dz = zv[r]-c.z;
                const float d2 = dx*dx + dy*dy + dz*dz;
                const float epg = __builtin_amdgcn_exp2f(l2p * d2) * c.w;
                const float ec  = __builtin_amdgcn_exp2f(l2c * d2);
                accd[r] += epg;
                const float sd = __builtin_amdgcn_sqrtf(fmaxf(d2, 1e-20f));
                accc[r] = fmaf(epg, sd, accc[r]);
                p[r] = fmaf(ec, rn, p[r]);
            }
        }
    }

    // ---- reductions ----
    #pragma unroll
    for (int r = 0; r < RPW; ++r) {
        #pragma unroll
        for (int off = 32; off >= 1; off >>= 1)
            accd[r] += __shfl_xor(accd[r], off, 64);
    }
    #pragma unroll
    for (int r = 0; r < RPW; ++r) {
        #pragma unroll
        for (int off = 32; off >= 1; off >>= 1)
            p[r] += __shfl_xor(p[r], off, 64);
    }
    // cost: fold wave-uniform f(s-1) into lane partials, one butterfly
    float fo[RPW];
    float cl = 0.f;
    #pragma unroll
    for (int r = 0; r < RPW; ++r) {
        fo[r] = fb[b * N_ + nw + r];        // 0 at s=0 (init) -> cost/rL no-ops
        cl = fmaf(fo[r], accc[r], cl);
    }
    #pragma unroll
    for (int off = 32; off >= 1; off >>= 1)
        cl += __shfl_xor(cl, off, 64);

    float rl_new[RPW], fn[RPW];
    #pragma unroll
    for (int r = 0; r < RPW; ++r) {
        const float rl = rLb[b * N_ + nw + r];
        rl_new[r] = fmaxf(rl - fo[r] * accd[r], 0.f);
        fn[r] = rl_new[r] * __builtin_amdgcn_rcpf(p[r] + EPS);
    }
    if (lane == 0) {
        if (has_p2) atomicAdd(&out[b], cl);
        if (has_p1) {
            #pragma unroll
            for (int r = 0; r < RPW; ++r) {
                const int idx = b * N_ + nw + r;
                fb[idx]  = fn[r];
                rLb[idx] = rl_new[r];
            }
        }
    }

    // ---- phase1 pass B: recompute e, per-lane column sums ----
    if (has_p1) {
        float ssp[32];
        #pragma unroll
        for (int k = 0; k < 32; ++k) {
            const int m = lane + (k << 6);
            const float4 c = spg[m];
            float s = 0.f;
            #pragma unroll
            for (int r = 0; r < RPW; ++r) {
                const float dx = xv[r]-c.x, dy = yv[r]-c.y, dz = zv[r]-c.z;
                const float d2 = dx*dx + dy*dy + dz*dz;
                s = fmaf(__builtin_amdgcn_exp2f(l2c * d2), fn[r], s);
            }
            ssp[k] = s * srn[m];
        }
        __syncthreads();   // all spg/srn reads done; ssl overlay safe
        #pragma unroll
        for (int k = 0; k < 32; ++k)
            ssl[wave * M_ + lane + (k << 6)] = ssp[k];
        __syncthreads();
        #pragma unroll
        for (int i = 0; i < MPT; ++i) {
            const int m = tid + i * THREADS;
            atomicAdd(&ssc_g[b * M_ + m],
                      ssl[m] + ssl[M_ + m] + ssl[2*M_ + m] + ssl[3*M_ + m]);
        }
    }
}

extern "C" void kernel_launch(void* const* d_in, const int* in_sizes, int n_in,
                              void* d_out, int out_size, void* d_ws, size_t ws_size,
                              hipStream_t stream) {
    const float* xyz1 = (const float*)d_in[0];
    const float* xyz2 = (const float*)d_in[1];
    float* out = (float*)d_out;
    float* ws = (float*)d_ws;
    const int SZ = B_ * N_;          // == B_*M_ == 16384
    float* rL  = ws;
    float* fb  = ws + SZ;
    float* rRb[2] = { ws + 2*SZ, ws + 3*SZ };
    float* ssb[3] = { ws + 4*SZ, ws + 5*SZ, ws + 6*SZ };

    init_kernel<<<(SZ + 255) / 256, 256, 0, stream>>>(rL, fb, ssb[0], out);

    constexpr float LOG2E = 1.4426950408889634f;
    static const float levels[10] = {
        -16384.f, -4096.f, -1024.f, -256.f, -64.f,
        -16.f, -4.f, -1.f, -0.25f, 0.f
    };
    // kernel s (s=0..10): phase2 of step s-1 (if s>0) + phase1 of step s (if s<10)
    // use_pow: for s<=8, levels[s-1] == 4*levels[s] (and s=0 only needs l2c),
    // so exp2(l2p*d2) = exp2(l2c*d2)^4. s=9 (l2c=0) and s=10 take the 2-exp path.
    for (int s = 0; s <= 10; ++s) {
        const int has_p2 = (s > 0);
        const int has_p1 = (s < 10);
        const int use_pow = (s <= 8);
        const float l2p = has_p2 ? levels[s-1] * LOG2E : 0.f;
        const float l2c = has_p1 ? levels[s]   * LOG2E : 0.f;
        fused_step<<<GRID, THREADS, 0, stream>>>(
            xyz1, xyz2, rL, fb,
            rRb[(s + 1) & 1],      // rR(s-1)
            rRb[s & 1],            // rR(s) out
            ssb[(s + 2) % 3],      // ss(s-1)
            ssb[s % 3],            // ss(s) accumulate (pre-zeroed)
            ssb[(s + 1) % 3],      // ss(s+1) zeroed for next kernel
            out, l2p, l2c, use_pow, has_p2, has_p1);
    }
}